// Round 1
// baseline (509.417 us; speedup 1.0000x reference)
//
#include <hip/hip_runtime.h>
#include <math.h>

typedef float4 f4;

static constexpr int kV = 10000, kL = 6, kO = 128, kE = 128, kDPL = 500;
static constexpr int kB = 64, kT = 32, kN = 40, kBT = 2048;
static constexpr int kVCHUNK = 2500;   // v-chunk for ontoV gemm (4 chunks)
static constexpr int kVT = 79;         // ceil(10000/128) v-tiles for loss gemm

#define FMA16                                                         \
    {                                                                 \
      f4 av = *(const f4*)&a_t[kk][rbase];                            \
      f4 wv = *(const f4*)&w_s[kk][cbase];                            \
      acc[0][0] += av.x * wv.x; acc[0][1] += av.x * wv.y;             \
      acc[0][2] += av.x * wv.z; acc[0][3] += av.x * wv.w;             \
      acc[1][0] += av.y * wv.x; acc[1][1] += av.y * wv.y;             \
      acc[1][2] += av.y * wv.z; acc[1][3] += av.y * wv.w;             \
      acc[2][0] += av.z * wv.x; acc[2][1] += av.z * wv.y;             \
      acc[2][2] += av.z * wv.z; acc[2][3] += av.z * wv.w;             \
      acc[3][0] += av.w * wv.x; acc[3][1] += av.w * wv.y;             \
      acc[3][2] += av.w * wv.z; acc[3][3] += av.w * wv.w;             \
    }

#define STORE_AT(kkb, rr_, v0, v1)                                    \
    a_t[(kkb)+0][rr_] = v0.x; a_t[(kkb)+1][rr_] = v0.y;               \
    a_t[(kkb)+2][rr_] = v0.z; a_t[(kkb)+3][rr_] = v0.w;               \
    a_t[(kkb)+4][rr_] = v1.x; a_t[(kkb)+5][rr_] = v1.y;               \
    a_t[(kkb)+6][rr_] = v1.z; a_t[(kkb)+7][rr_] = v1.w;

// ---------------- ehrV = l2norm(sum_n ehr_table[dxseqs]) ----------------
__global__ __launch_bounds__(128) void mmore_ehrv(
    const int* __restrict__ dxseqs, const float* __restrict__ ehr_table,
    float* __restrict__ ehrV) {
  int bt = blockIdx.x, t = threadIdx.x;
  const int* row = dxseqs + bt * kN;
  float acc = 0.f;
  for (int n = 0; n < kN; ++n) acc += ehr_table[(size_t)row[n] * kE + t];
  float v = acc * acc;
  #pragma unroll
  for (int off = 32; off; off >>= 1) v += __shfl_down(v, off);
  __shared__ float red[2];
  if ((t & 63) == 0) red[t >> 6] = v;
  __syncthreads();
  float ss = red[0] + red[1];
  float inv = 1.f / fmaxf(sqrtf(ss), 1e-12f);
  ehrV[bt * kE + t] = acc * inv;
}

// ---------------- GRAM scores: s[v*6+l] = Wc . tanh([el,ea]@Wa + ba) + bc ----
__global__ __launch_bounds__(256) void mmore_scores(
    const float* __restrict__ ot, const int* __restrict__ leaves,
    const int* __restrict__ anc, const float* __restrict__ Wa,
    const float* __restrict__ ba, const float* __restrict__ Wc,
    const float* __restrict__ bc, float* __restrict__ s_out) {
  __shared__ __align__(16) float a_t[64][36];
  __shared__ __align__(16) float w_s[64][128];
  __shared__ int lidx[32], aidx[32];
  int t = threadIdx.x;
  int r0 = blockIdx.x * 32;
  if (t < 32) {
    int row = r0 + t;
    int v = row / 6, l = row - v * 6;
    lidx[t] = leaves[v * kL + l];
    aidx[t] = anc[v * kL + l];
  }
  __syncthreads();
  int rg = t >> 5, cg = t & 31, rbase = rg * 4, cbase = cg * 4;
  int rr = t >> 3, kk0 = (t & 7) * 8;
  float acc[4][4] = {};
  for (int q = 0; q < 4; ++q) {
    const float* srow = (q < 2) ? (ot + (size_t)lidx[rr] * kO + q * 64)
                                : (ot + (size_t)aidx[rr] * kO + (q - 2) * 64);
    f4 x0 = *(const f4*)(srow + kk0);
    f4 x1 = *(const f4*)(srow + kk0 + 4);
    STORE_AT(kk0, rr, x0, x1);
    const f4* wsrc = (const f4*)(Wa + q * 64 * 128);
    f4* wdst = (f4*)&w_s[0][0];
    #pragma unroll
    for (int i = 0; i < 8; ++i) wdst[t + i * 256] = wsrc[t + i * 256];
    __syncthreads();
    #pragma unroll 4
    for (int kk = 0; kk < 64; ++kk) FMA16;
    __syncthreads();
  }
  float bcv = bc[0];
  #pragma unroll
  for (int i = 0; i < 4; ++i) {
    float p = 0.f;
    #pragma unroll
    for (int j = 0; j < 4; ++j) {
      int c = cbase + j;
      p += tanhf(acc[i][j] + ba[c]) * Wc[c];
    }
    #pragma unroll
    for (int off = 16; off; off >>= 1) p += __shfl_xor(p, off);
    if (cg == 0) s_out[r0 + rbase + i] = p + bcv;
  }
}

// ---------------- onto_all[v] = softmax_l(s) . ea ; row V = 0 ----------------
__global__ __launch_bounds__(128) void mmore_onto(
    const float* __restrict__ ot, const int* __restrict__ anc,
    const float* __restrict__ s_in, float* __restrict__ onto_all) {
  int v = blockIdx.x, t = threadIdx.x;
  if (v == kV) { onto_all[(size_t)v * kO + t] = 0.f; return; }
  __shared__ float sv[kL];
  __shared__ int aidx[kL];
  if (t < kL) { sv[t] = s_in[v * kL + t]; aidx[t] = anc[v * kL + t]; }
  __syncthreads();
  float mx = sv[0];
  #pragma unroll
  for (int l = 1; l < kL; ++l) mx = fmaxf(mx, sv[l]);
  float e[kL], sum = 0.f;
  #pragma unroll
  for (int l = 0; l < kL; ++l) { e[l] = expf(sv[l] - mx); sum += e[l]; }
  float acc = 0.f;
  #pragma unroll
  for (int l = 0; l < kL; ++l)
    acc += (e[l] / sum) * ot[(size_t)aidx[l] * kO + t];
  onto_all[(size_t)v * kO + t] = acc;
}

// ---------------- ontoV partials: X(bt,v) @ onto_all(v,128), v-chunked ----------
__global__ __launch_bounds__(256) void mmore_ontov(
    const float* __restrict__ X, const float* __restrict__ W,
    float* __restrict__ part) {
  __shared__ __align__(16) float a_t[64][36];
  __shared__ __align__(16) float w_s[64][128];
  int t = threadIdx.x;
  int btile = blockIdx.x & 63;
  int chunk = blockIdx.x >> 6;
  int r0 = btile * 32;
  int vbase = chunk * kVCHUNK;
  int rg = t >> 5, cg = t & 31, rbase = rg * 4, cbase = cg * 4;
  int rr = t >> 3, kk0 = (t & 7) * 8;
  int sbt = r0 + rr;
  const float* xrow = X + ((size_t)(sbt & 31) * kB + (sbt >> 5)) * kV + vbase;
  float acc[4][4] = {};
  for (int k0 = 0; k0 < kVCHUNK; k0 += 64) {
    #pragma unroll
    for (int u4 = 0; u4 < 8; u4 += 4) {
      f4 xv = make_float4(0.f, 0.f, 0.f, 0.f);
      if (k0 + kk0 + u4 < kVCHUNK) xv = *(const f4*)(xrow + k0 + kk0 + u4);
      a_t[kk0 + u4 + 0][rr] = xv.x; a_t[kk0 + u4 + 1][rr] = xv.y;
      a_t[kk0 + u4 + 2][rr] = xv.z; a_t[kk0 + u4 + 3][rr] = xv.w;
    }
    #pragma unroll
    for (int i = 0; i < 8; ++i) {
      int f = t + i * 256;
      int kk = f >> 5, c4 = f & 31;
      f4 wv = make_float4(0.f, 0.f, 0.f, 0.f);
      if (k0 + kk < kVCHUNK)
        wv = ((const f4*)(W + (size_t)(vbase + k0 + kk) * kO))[c4];
      ((f4*)&w_s[0][0])[f] = wv;
    }
    __syncthreads();
    #pragma unroll 4
    for (int kk = 0; kk < 64; ++kk) FMA16;
    __syncthreads();
  }
  #pragma unroll
  for (int i = 0; i < 4; ++i) {
    int obt = r0 + rbase + i;
    *(f4*)(part + ((size_t)chunk * kBT + obt) * kO + cbase) =
        make_float4(acc[i][0], acc[i][1], acc[i][2], acc[i][3]);
  }
}

__global__ __launch_bounds__(256) void mmore_creduce(
    const float* __restrict__ part, float* __restrict__ out) {
  int i = blockIdx.x * 256 + threadIdx.x;
  const int S = kBT * kO;
  out[i] = part[i] + part[S + i] + part[2 * S + i] + part[3 * S + i];
}

// ---------------- generic C[M,128] = [C +] A[M,128]@W[128,128] [+ bias] ------
__global__ __launch_bounds__(256) void mmore_gemm128(
    const float* __restrict__ A, const float* __restrict__ W,
    const float* __restrict__ bias, float* __restrict__ C,
    int M, int accumulate) {
  __shared__ __align__(16) float a_t[64][36];
  __shared__ __align__(16) float w_s[64][128];
  int t = threadIdx.x;
  int r0 = blockIdx.x * 32;
  int rg = t >> 5, cg = t & 31, rbase = rg * 4, cbase = cg * 4;
  int rr = t >> 3, kk0 = (t & 7) * 8;
  int row = r0 + rr;
  float acc[4][4] = {};
  for (int q = 0; q < 2; ++q) {
    f4 x0 = make_float4(0.f, 0.f, 0.f, 0.f), x1 = x0;
    if (row < M) {
      const float* s = A + (size_t)row * 128 + q * 64 + kk0;
      x0 = *(const f4*)s; x1 = *(const f4*)(s + 4);
    }
    STORE_AT(kk0, rr, x0, x1);
    const f4* wsrc = (const f4*)(W + q * 64 * 128);
    f4* wdst = (f4*)&w_s[0][0];
    #pragma unroll
    for (int i = 0; i < 8; ++i) wdst[t + i * 256] = wsrc[t + i * 256];
    __syncthreads();
    #pragma unroll 4
    for (int kk = 0; kk < 64; ++kk) FMA16;
    __syncthreads();
  }
  #pragma unroll
  for (int i = 0; i < 4; ++i) {
    int orow = r0 + rbase + i;
    if (orow >= M) continue;
    #pragma unroll
    for (int j = 0; j < 4; ++j) {
      int c = cbase + j;
      float val = acc[i][j];
      if (bias) val += bias[c];
      if (accumulate) val += C[(size_t)orow * 128 + c];
      C[(size_t)orow * 128 + c] = val;
    }
  }
}

// ---------------- loss gemm: z = ehrV@coW + cob, partial {sum e^z, sum p*z, sum p}
__global__ __launch_bounds__(256) void mmore_lossgemm(
    const float* __restrict__ ehrV, const float* __restrict__ coW,
    const float* __restrict__ cob, const float* __restrict__ X,
    float* __restrict__ epart) {
  __shared__ __align__(16) float a_t[64][36];
  __shared__ __align__(16) float w_s[64][128];
  int t = threadIdx.x;
  int btile = blockIdx.x & 63;
  int vtile = blockIdx.x >> 6;
  int r0 = btile * 32, vb = vtile * 128;
  int rg = t >> 5, cg = t & 31, rbase = rg * 4, cbase = cg * 4;
  int rr = t >> 3, kk0 = (t & 7) * 8;
  float acc[4][4] = {};
  for (int q = 0; q < 2; ++q) {
    const float* s = ehrV + (size_t)(r0 + rr) * 128 + q * 64 + kk0;
    f4 x0 = *(const f4*)s, x1 = *(const f4*)(s + 4);
    STORE_AT(kk0, rr, x0, x1);
    #pragma unroll
    for (int i = 0; i < 8; ++i) {
      int f = t + i * 256;
      int kk = f >> 5, c4 = f & 31;
      int v = vb + c4 * 4;
      f4 wv = make_float4(0.f, 0.f, 0.f, 0.f);
      if (v < kV) wv = *(const f4*)(coW + (size_t)(q * 64 + kk) * kV + v);
      ((f4*)&w_s[0][0])[f] = wv;
    }
    __syncthreads();
    #pragma unroll 4
    for (int kk = 0; kk < 64; ++kk) FMA16;
    __syncthreads();
  }
  float se[4] = {}, spz[4] = {}, sp[4] = {};
  int vcol = vb + cbase;
  bool okc = (vcol < kV);
  #pragma unroll
  for (int i = 0; i < 4; ++i) {
    if (!okc) break;
    int bt = r0 + rbase + i;
    const float* xrow = X + ((size_t)(bt & 31) * kB + (bt >> 5)) * kV;
    f4 p = *(const f4*)(xrow + vcol);
    float z0 = acc[i][0] + cob[vcol + 0];
    float z1 = acc[i][1] + cob[vcol + 1];
    float z2 = acc[i][2] + cob[vcol + 2];
    float z3 = acc[i][3] + cob[vcol + 3];
    se[i] = expf(z0) + expf(z1) + expf(z2) + expf(z3);
    spz[i] = p.x * z0 + p.y * z1 + p.z * z2 + p.w * z3;
    sp[i] = p.x + p.y + p.z + p.w;
  }
  #pragma unroll
  for (int i = 0; i < 4; ++i) {
    #pragma unroll
    for (int off = 16; off; off >>= 1) {
      se[i] += __shfl_xor(se[i], off);
      spz[i] += __shfl_xor(spz[i], off);
      sp[i] += __shfl_xor(sp[i], off);
    }
  }
  if (cg == 0) {
    #pragma unroll
    for (int i = 0; i < 4; ++i) {
      int bt = r0 + rbase + i;
      size_t o = ((size_t)vtile * kBT + bt) * 3;
      epart[o] = se[i]; epart[o + 1] = spz[i]; epart[o + 2] = sp[i];
    }
  }
}

__global__ __launch_bounds__(256) void mmore_ereduce(
    const float* __restrict__ epart, float* __restrict__ term) {
  int bt = blockIdx.x * 256 + threadIdx.x;
  float S = 0.f, PZ = 0.f, PS = 0.f;
  for (int c = 0; c < kVT; ++c) {
    size_t o = ((size_t)c * kBT + bt) * 3;
    S += epart[o]; PZ += epart[o + 1]; PS += epart[o + 2];
  }
  term[bt] = PZ - PS * logf(S);
}

__global__ __launch_bounds__(256) void mmore_lossfin(
    const float* __restrict__ term, float* __restrict__ out) {
  int t = threadIdx.x;
  float a = 0.f;
  for (int i = t; i < kBT; i += 256) a += term[i];
  #pragma unroll
  for (int off = 32; off; off >>= 1) a += __shfl_down(a, off);
  __shared__ float red[4];
  if ((t & 63) == 0) red[t >> 6] = a;
  __syncthreads();
  if (t == 0) out[0] = -(10.f / 64.f) * (red[0] + red[1] + red[2] + red[3]);
}

// ---------------- per-(b,t): Bahdanau attention over 40 codes + dp head ------
__device__ __forceinline__ float mmore_block_sum(float v, float* red) {
  int t = threadIdx.x;
  #pragma unroll
  for (int off = 32; off; off >>= 1) v += __shfl_down(v, off);
  if ((t & 63) == 0) red[t >> 6] = v;
  __syncthreads();
  if (t == 0) red[0] = red[0] + red[1] + red[2] + red[3];
  __syncthreads();
  return red[0];
}

__global__ __launch_bounds__(256) void mmore_attn_dp(
    const int* __restrict__ dxseqs, const float* __restrict__ base,
    const float* __restrict__ pe, const float* __restrict__ po,
    const float* __restrict__ combW, const float* __restrict__ combB,
    const float* __restrict__ ehr_table, const float* __restrict__ onto_all,
    const float* __restrict__ dpW, const float* __restrict__ dpB,
    float* __restrict__ out) {
  __shared__ float base_s[128];
  __shared__ int idx_s[kN];
  __shared__ float scp[kN][2];
  __shared__ float attn_s[64];
  __shared__ float tn_s[256];
  __shared__ __align__(16) float up[2][kDPL];
  __shared__ __align__(16) float e_s[kDPL];
  __shared__ float red[4];
  int bt = blockIdx.x, t = threadIdx.x;
  if (t < 128) base_s[t] = base[bt * 128 + t];
  if (t < kN) idx_s[t] = dxseqs[bt * kN + t];
  __syncthreads();
  int c = t & 127, half = t >> 7, wid = t >> 6, lane = t & 63;
  float cw = combW[c];
  for (int n2 = 0; n2 < kN / 2; ++n2) {
    int n = n2 * 2 + half;
    int id = idx_s[n];
    float x = base_s[c] + pe[(size_t)id * 128 + c] + po[(size_t)id * 128 + c];
    float val = tanhf(x) * cw;
    #pragma unroll
    for (int off = 32; off; off >>= 1) val += __shfl_down(val, off);
    if (lane == 0) scp[n][wid & 1] = val;
  }
  __syncthreads();
  if (t < 64) {
    float s = (t < kN) ? (scp[t][0] + scp[t][1] + combB[0]) : -1e30f;
    float mx = s;
    #pragma unroll
    for (int off = 32; off; off >>= 1) mx = fmaxf(mx, __shfl_xor(mx, off));
    float e = (t < kN) ? expf(s - mx) : 0.f;
    float sm = e;
    #pragma unroll
    for (int off = 32; off; off >>= 1) sm += __shfl_xor(sm, off);
    attn_s[t] = e / sm;
  }
  __syncthreads();
  float acc = 0.f;
  {
    const float* tab = (t < 128) ? ehr_table : onto_all;
    int j = t & 127;
    for (int n = 0; n < kN; ++n)
      acc += attn_s[n] * tab[(size_t)idx_s[n] * 128 + j];
  }
  float ss = mmore_block_sum(acc * acc, red);
  float inv = 1.f / fmaxf(sqrtf(ss), 1e-12f);
  tn_s[t] = tanhf(acc * inv);
  __syncthreads();
  if (t < 250) {
    int j4 = (t % 125) * 4, kh = t / 125;
    float ax = 0.f, ay = 0.f, az = 0.f, aw = 0.f;
    const float* wp = dpW + j4;
    for (int k = kh * 128; k < kh * 128 + 128; ++k) {
      float tv = tn_s[k];
      f4 w4 = *(const f4*)(wp + (size_t)k * kDPL);
      ax += tv * w4.x; ay += tv * w4.y; az += tv * w4.z; aw += tv * w4.w;
    }
    *(f4*)&up[kh][j4] = make_float4(ax, ay, az, aw);
  }
  __syncthreads();
  float psum = 0.f;
  if (t < 125) {
    int j4 = t * 4;
    float u0 = up[0][j4 + 0] + up[1][j4 + 0] + dpB[j4 + 0];
    float u1 = up[0][j4 + 1] + up[1][j4 + 1] + dpB[j4 + 1];
    float u2 = up[0][j4 + 2] + up[1][j4 + 2] + dpB[j4 + 2];
    float u3 = up[0][j4 + 3] + up[1][j4 + 3] + dpB[j4 + 3];
    float e0 = expf(u0), e1 = expf(u1), e2 = expf(u2), e3 = expf(u3);
    *(f4*)&e_s[j4] = make_float4(e0, e1, e2, e3);
    psum = e0 + e1 + e2 + e3;
  }
  float S = mmore_block_sum(psum, red);
  if (t < 125) {
    float invS = 1.f / S;
    f4 e = *(const f4*)&e_s[t * 4];
    *(f4*)(out + (size_t)bt * kDPL + t * 4) =
        make_float4(e.x * invS, e.y * invS, e.z * invS, e.w * invS);
  }
}

extern "C" void kernel_launch(void* const* d_in, const int* in_sizes, int n_in,
                              void* d_out, int out_size, void* d_ws, size_t ws_size,
                              hipStream_t stream) {
  const int*   dxseqs     = (const int*)d_in[0];
  const float* dx_onehot  = (const float*)d_in[1];
  const int*   leaves     = (const int*)d_in[2];
  const int*   ancestors  = (const int*)d_in[3];
  const float* onto_table = (const float*)d_in[4];
  const float* onto_Wa    = (const float*)d_in[5];
  const float* onto_ba    = (const float*)d_in[6];
  const float* onto_Wc    = (const float*)d_in[7];
  const float* onto_bc    = (const float*)d_in[8];
  const float* ehr_table  = (const float*)d_in[9];
  const float* attn_W     = (const float*)d_in[10];
  const float* attn_b     = (const float*)d_in[11];
  const float* comb_W     = (const float*)d_in[12];
  const float* comb_b     = (const float*)d_in[13];
  const float* co_W       = (const float*)d_in[14];
  const float* co_b       = (const float*)d_in[15];
  const float* dp_W       = (const float*)d_in[16];
  const float* dp_b       = (const float*)d_in[17];
  float* out = (float*)d_out;

  // workspace layout (floats) — total ~6.23M floats (~25 MB)
  float* ws = (float*)d_ws;
  float* onto_all = ws;  ws += (size_t)(kV + 1) * kO;   // 1280128
  float* s_sc = ws;      ws += (size_t)kV * kL;         // 60000
  float* ehrV = ws;      ws += (size_t)kBT * kE;        // 262144
  float* ontoV = ws;     ws += (size_t)kBT * kO;        // 262144
  float* cpart = ws;     ws += (size_t)4 * kBT * kO;    // 1048576
  float* pe = ws;        ws += (size_t)(kV + 1) * 128;  // 1280128
  float* po = ws;        ws += (size_t)(kV + 1) * 128;  // 1280128
  float* basep = ws;     ws += (size_t)kBT * 128;       // 262144
  float* epart = ws;     ws += (size_t)kVT * kBT * 3;   // 485376
  float* term = ws;      ws += kBT;                     // 2048

  mmore_ehrv<<<kBT, 128, 0, stream>>>(dxseqs, ehr_table, ehrV);
  mmore_scores<<<(kV * kL) / 32, 256, 0, stream>>>(onto_table, leaves, ancestors,
                                                   onto_Wa, onto_ba, onto_Wc, onto_bc, s_sc);
  mmore_onto<<<kV + 1, 128, 0, stream>>>(onto_table, ancestors, s_sc, onto_all);
  mmore_ontov<<<64 * 4, 256, 0, stream>>>(dx_onehot, onto_all, cpart);
  mmore_creduce<<<(kBT * kO) / 256, 256, 0, stream>>>(cpart, ontoV);
  mmore_gemm128<<<313, 256, 0, stream>>>(ehr_table, attn_W + 256 * 128, nullptr, pe, kV + 1, 0);
  mmore_gemm128<<<313, 256, 0, stream>>>(onto_all, attn_W + 384 * 128, nullptr, po, kV + 1, 0);
  mmore_gemm128<<<64, 256, 0, stream>>>(ontoV, attn_W, nullptr, basep, kBT, 0);
  mmore_gemm128<<<64, 256, 0, stream>>>(ehrV, attn_W + 128 * 128, attn_b, basep, kBT, 1);
  mmore_lossgemm<<<64 * kVT, 256, 0, stream>>>(ehrV, co_W, co_b, dx_onehot, epart);
  mmore_ereduce<<<kBT / 256, 256, 0, stream>>>(epart, term);
  mmore_lossfin<<<1, 256, 0, stream>>>(term, out + (size_t)kBT * kDPL);
  mmore_attn_dp<<<kBT, 256, 0, stream>>>(dxseqs, basep, pe, po, comb_W, comb_b,
                                         ehr_table, onto_all, dp_W, dp_b, out);
}

// Round 2
// 417.356 us; speedup vs baseline: 1.2206x; 1.2206x over previous
//
#include <hip/hip_runtime.h>
#include <math.h>

typedef float4 f4;

static constexpr int kV = 10000, kL = 6, kO = 128, kE = 128, kDPL = 500;
static constexpr int kB = 64, kT = 32, kN = 40, kBT = 2048;
static constexpr int kC = 12, kKPER = 896;   // K-split for ontoV gemm (12 chunks of 896)
static constexpr int kVT = 79;               // ceil(10000/128) v-tiles for loss gemm

#define FMA16                                                         \
    {                                                                 \
      f4 av = *(const f4*)&a_t[kk][rbase];                            \
      f4 wv = *(const f4*)&w_s[kk][cbase];                            \
      acc[0][0] += av.x * wv.x; acc[0][1] += av.x * wv.y;             \
      acc[0][2] += av.x * wv.z; acc[0][3] += av.x * wv.w;             \
      acc[1][0] += av.y * wv.x; acc[1][1] += av.y * wv.y;             \
      acc[1][2] += av.y * wv.z; acc[1][3] += av.y * wv.w;             \
      acc[2][0] += av.z * wv.x; acc[2][1] += av.z * wv.y;             \
      acc[2][2] += av.z * wv.z; acc[2][3] += av.z * wv.w;             \
      acc[3][0] += av.w * wv.x; acc[3][1] += av.w * wv.y;             \
      acc[3][2] += av.w * wv.z; acc[3][3] += av.w * wv.w;             \
    }

#define STORE_AT(kkb, rr_, v0, v1)                                    \
    a_t[(kkb)+0][rr_] = v0.x; a_t[(kkb)+1][rr_] = v0.y;               \
    a_t[(kkb)+2][rr_] = v0.z; a_t[(kkb)+3][rr_] = v0.w;               \
    a_t[(kkb)+4][rr_] = v1.x; a_t[(kkb)+5][rr_] = v1.y;               \
    a_t[(kkb)+6][rr_] = v1.z; a_t[(kkb)+7][rr_] = v1.w;

// ---------------- ehrV = l2norm(sum_n ehr_table[dxseqs]) ----------------
__global__ __launch_bounds__(128) void mmore_ehrv(
    const int* __restrict__ dxseqs, const float* __restrict__ ehr_table,
    float* __restrict__ ehrV) {
  int bt = blockIdx.x, t = threadIdx.x;
  const int* row = dxseqs + bt * kN;
  float acc = 0.f;
  for (int n = 0; n < kN; ++n) acc += ehr_table[(size_t)row[n] * kE + t];
  float v = acc * acc;
  #pragma unroll
  for (int off = 32; off; off >>= 1) v += __shfl_down(v, off);
  __shared__ float red[2];
  if ((t & 63) == 0) red[t >> 6] = v;
  __syncthreads();
  float ss = red[0] + red[1];
  float inv = 1.f / fmaxf(sqrtf(ss), 1e-12f);
  ehrV[bt * kE + t] = acc * inv;
}

// ---------------- GRAM scores: s[v*6+l] = Wc . tanh([el,ea]@Wa + ba) + bc ----
__global__ __launch_bounds__(256) void mmore_scores(
    const float* __restrict__ ot, const int* __restrict__ leaves,
    const int* __restrict__ anc, const float* __restrict__ Wa,
    const float* __restrict__ ba, const float* __restrict__ Wc,
    const float* __restrict__ bc, float* __restrict__ s_out) {
  __shared__ __align__(16) float a_t[64][36];
  __shared__ __align__(16) float w_s[64][128];
  __shared__ int lidx[32], aidx[32];
  int t = threadIdx.x;
  int r0 = blockIdx.x * 32;
  if (t < 32) {
    int row = r0 + t;
    int v = row / 6, l = row - v * 6;
    lidx[t] = leaves[v * kL + l];
    aidx[t] = anc[v * kL + l];
  }
  __syncthreads();
  int rg = t >> 5, cg = t & 31, rbase = rg * 4, cbase = cg * 4;
  int rr = t >> 3, kk0 = (t & 7) * 8;
  float acc[4][4] = {};
  for (int q = 0; q < 4; ++q) {
    const float* srow = (q < 2) ? (ot + (size_t)lidx[rr] * kO + q * 64)
                                : (ot + (size_t)aidx[rr] * kO + (q - 2) * 64);
    f4 x0 = *(const f4*)(srow + kk0);
    f4 x1 = *(const f4*)(srow + kk0 + 4);
    STORE_AT(kk0, rr, x0, x1);
    const f4* wsrc = (const f4*)(Wa + q * 64 * 128);
    f4* wdst = (f4*)&w_s[0][0];
    #pragma unroll
    for (int i = 0; i < 8; ++i) wdst[t + i * 256] = wsrc[t + i * 256];
    __syncthreads();
    #pragma unroll 4
    for (int kk = 0; kk < 64; ++kk) FMA16;
    __syncthreads();
  }
  float bcv = bc[0];
  #pragma unroll
  for (int i = 0; i < 4; ++i) {
    float p = 0.f;
    #pragma unroll
    for (int j = 0; j < 4; ++j) {
      int c = cbase + j;
      p += tanhf(acc[i][j] + ba[c]) * Wc[c];
    }
    #pragma unroll
    for (int off = 16; off; off >>= 1) p += __shfl_xor(p, off);
    if (cg == 0) s_out[r0 + rbase + i] = p + bcv;
  }
}

// ---------------- onto_all[v] = softmax_l(s) . ea ; row V = 0 ----------------
__global__ __launch_bounds__(128) void mmore_onto(
    const float* __restrict__ ot, const int* __restrict__ anc,
    const float* __restrict__ s_in, float* __restrict__ onto_all) {
  int v = blockIdx.x, t = threadIdx.x;
  if (v == kV) { onto_all[(size_t)v * kO + t] = 0.f; return; }
  __shared__ float sv[kL];
  __shared__ int aidx[kL];
  if (t < kL) { sv[t] = s_in[v * kL + t]; aidx[t] = anc[v * kL + t]; }
  __syncthreads();
  float mx = sv[0];
  #pragma unroll
  for (int l = 1; l < kL; ++l) mx = fmaxf(mx, sv[l]);
  float e[kL], sum = 0.f;
  #pragma unroll
  for (int l = 0; l < kL; ++l) { e[l] = expf(sv[l] - mx); sum += e[l]; }
  float acc = 0.f;
  #pragma unroll
  for (int l = 0; l < kL; ++l)
    acc += (e[l] / sum) * ot[(size_t)aidx[l] * kO + t];
  onto_all[(size_t)v * kO + t] = acc;
}

// ---------------- ontoV partials: X(bt,v) @ onto_all(v,128), 12-way K-split ----
__global__ __launch_bounds__(256) void mmore_ontov(
    const float* __restrict__ X, const float* __restrict__ W,
    float* __restrict__ part) {
  __shared__ __align__(16) float a_t[64][36];
  __shared__ __align__(16) float w_s[64][128];
  int t = threadIdx.x;
  int btile = blockIdx.x & 63;            // 64 row-tiles of 32
  int chunk = blockIdx.x >> 6;            // 12 K-chunks of 896
  int r0 = btile * 32;
  int vbase = chunk * kKPER;
  int Klim = kV - vbase; if (Klim > kKPER) Klim = kKPER;
  int rg = t >> 5, cg = t & 31, rbase = rg * 4, cbase = cg * 4;
  int srow = t >> 3;                      // staging row 0..31
  int sk = (t & 7) * 4;                   // staging k base (coalesced 128B/8 lanes)
  int sbt = r0 + srow;
  const float* xrow = X + ((size_t)(sbt & 31) * kB + (sbt >> 5)) * kV + vbase;
  float acc[4][4] = {};
  for (int k0 = 0; k0 < Klim; k0 += 64) {
    #pragma unroll
    for (int u = 0; u < 2; ++u) {
      int lk = sk + u * 32;               // 0..63 within phase
      f4 xv = make_float4(0.f, 0.f, 0.f, 0.f);
      if (k0 + lk < Klim) xv = *(const f4*)(xrow + k0 + lk);
      a_t[lk + 0][srow] = xv.x; a_t[lk + 1][srow] = xv.y;
      a_t[lk + 2][srow] = xv.z; a_t[lk + 3][srow] = xv.w;
    }
    #pragma unroll
    for (int i = 0; i < 8; ++i) {
      int f = t + i * 256;
      int kk = f >> 5, c4 = f & 31;
      f4 wv = make_float4(0.f, 0.f, 0.f, 0.f);
      if (k0 + kk < Klim)
        wv = ((const f4*)(W + (size_t)(vbase + k0 + kk) * kO))[c4];
      ((f4*)&w_s[0][0])[f] = wv;
    }
    __syncthreads();
    #pragma unroll 4
    for (int kk = 0; kk < 64; ++kk) FMA16;
    __syncthreads();
  }
  #pragma unroll
  for (int i = 0; i < 4; ++i) {
    int obt = r0 + rbase + i;
    *(f4*)(part + ((size_t)chunk * kBT + obt) * kO + cbase) =
        make_float4(acc[i][0], acc[i][1], acc[i][2], acc[i][3]);
  }
}

__global__ __launch_bounds__(256) void mmore_creduce(
    const float* __restrict__ part, float* __restrict__ out) {
  int i = blockIdx.x * 256 + threadIdx.x;
  const int S = kBT * kO;
  float a = 0.f;
  #pragma unroll
  for (int c = 0; c < kC; ++c) a += part[(size_t)c * S + i];
  out[i] = a;
}

// ---------------- generic C[M,128] = [C +] A[M,128]@W[128,128] [+ bias] ------
__global__ __launch_bounds__(256) void mmore_gemm128(
    const float* __restrict__ A, const float* __restrict__ W,
    const float* __restrict__ bias, float* __restrict__ C,
    int M, int accumulate) {
  __shared__ __align__(16) float a_t[64][36];
  __shared__ __align__(16) float w_s[64][128];
  int t = threadIdx.x;
  int r0 = blockIdx.x * 32;
  int rg = t >> 5, cg = t & 31, rbase = rg * 4, cbase = cg * 4;
  int rr = t >> 3, kk0 = (t & 7) * 8;
  int row = r0 + rr;
  float acc[4][4] = {};
  for (int q = 0; q < 2; ++q) {
    f4 x0 = make_float4(0.f, 0.f, 0.f, 0.f), x1 = x0;
    if (row < M) {
      const float* s = A + (size_t)row * 128 + q * 64 + kk0;
      x0 = *(const f4*)s; x1 = *(const f4*)(s + 4);
    }
    STORE_AT(kk0, rr, x0, x1);
    const f4* wsrc = (const f4*)(W + q * 64 * 128);
    f4* wdst = (f4*)&w_s[0][0];
    #pragma unroll
    for (int i = 0; i < 8; ++i) wdst[t + i * 256] = wsrc[t + i * 256];
    __syncthreads();
    #pragma unroll 4
    for (int kk = 0; kk < 64; ++kk) FMA16;
    __syncthreads();
  }
  #pragma unroll
  for (int i = 0; i < 4; ++i) {
    int orow = r0 + rbase + i;
    if (orow >= M) continue;
    #pragma unroll
    for (int j = 0; j < 4; ++j) {
      int c = cbase + j;
      float val = acc[i][j];
      if (bias) val += bias[c];
      if (accumulate) val += C[(size_t)orow * 128 + c];
      C[(size_t)orow * 128 + c] = val;
    }
  }
}

// ---------------- loss gemm: z = ehrV@coW + cob, partial {sum e^z, sum p*z, sum p}
__global__ __launch_bounds__(256) void mmore_lossgemm(
    const float* __restrict__ ehrV, const float* __restrict__ coW,
    const float* __restrict__ cob, const float* __restrict__ X,
    float* __restrict__ epart) {
  __shared__ __align__(16) float a_t[64][36];
  __shared__ __align__(16) float w_s[64][128];
  int t = threadIdx.x;
  int btile = blockIdx.x & 63;
  int vtile = blockIdx.x >> 6;
  int r0 = btile * 32, vb = vtile * 128;
  int rg = t >> 5, cg = t & 31, rbase = rg * 4, cbase = cg * 4;
  int rr = t >> 3, kk0 = (t & 7) * 8;
  float acc[4][4] = {};
  for (int q = 0; q < 2; ++q) {
    const float* s = ehrV + (size_t)(r0 + rr) * 128 + q * 64 + kk0;
    f4 x0 = *(const f4*)s, x1 = *(const f4*)(s + 4);
    STORE_AT(kk0, rr, x0, x1);
    #pragma unroll
    for (int i = 0; i < 8; ++i) {
      int f = t + i * 256;
      int kk = f >> 5, c4 = f & 31;
      int v = vb + c4 * 4;
      f4 wv = make_float4(0.f, 0.f, 0.f, 0.f);
      if (v < kV) wv = *(const f4*)(coW + (size_t)(q * 64 + kk) * kV + v);
      ((f4*)&w_s[0][0])[f] = wv;
    }
    __syncthreads();
    #pragma unroll 4
    for (int kk = 0; kk < 64; ++kk) FMA16;
    __syncthreads();
  }
  float se[4] = {}, spz[4] = {}, sp[4] = {};
  int vcol = vb + cbase;
  bool okc = (vcol < kV);
  #pragma unroll
  for (int i = 0; i < 4; ++i) {
    if (!okc) break;
    int bt = r0 + rbase + i;
    const float* xrow = X + ((size_t)(bt & 31) * kB + (bt >> 5)) * kV;
    f4 p = *(const f4*)(xrow + vcol);
    float z0 = acc[i][0] + cob[vcol + 0];
    float z1 = acc[i][1] + cob[vcol + 1];
    float z2 = acc[i][2] + cob[vcol + 2];
    float z3 = acc[i][3] + cob[vcol + 3];
    se[i] = expf(z0) + expf(z1) + expf(z2) + expf(z3);
    spz[i] = p.x * z0 + p.y * z1 + p.z * z2 + p.w * z3;
    sp[i] = p.x + p.y + p.z + p.w;
  }
  #pragma unroll
  for (int i = 0; i < 4; ++i) {
    #pragma unroll
    for (int off = 16; off; off >>= 1) {
      se[i] += __shfl_xor(se[i], off);
      spz[i] += __shfl_xor(spz[i], off);
      sp[i] += __shfl_xor(sp[i], off);
    }
  }
  if (cg == 0) {
    #pragma unroll
    for (int i = 0; i < 4; ++i) {
      int bt = r0 + rbase + i;
      size_t o = ((size_t)vtile * kBT + bt) * 3;
      epart[o] = se[i]; epart[o + 1] = spz[i]; epart[o + 2] = sp[i];
    }
  }
}

__global__ __launch_bounds__(256) void mmore_ereduce(
    const float* __restrict__ epart, float* __restrict__ term) {
  int bt = blockIdx.x * 256 + threadIdx.x;
  float S = 0.f, PZ = 0.f, PS = 0.f;
  for (int c = 0; c < kVT; ++c) {
    size_t o = ((size_t)c * kBT + bt) * 3;
    S += epart[o]; PZ += epart[o + 1]; PS += epart[o + 2];
  }
  term[bt] = PZ - PS * logf(S);
}

__global__ __launch_bounds__(256) void mmore_lossfin(
    const float* __restrict__ term, float* __restrict__ out) {
  int t = threadIdx.x;
  float a = 0.f;
  for (int i = t; i < kBT; i += 256) a += term[i];
  #pragma unroll
  for (int off = 32; off; off >>= 1) a += __shfl_down(a, off);
  __shared__ float red[4];
  if ((t & 63) == 0) red[t >> 6] = a;
  __syncthreads();
  if (t == 0) out[0] = -(10.f / 64.f) * (red[0] + red[1] + red[2] + red[3]);
}

// ---------------- per-(b,t): Bahdanau attention over 40 codes + dp head ------
__device__ __forceinline__ float mmore_block_sum(float v, float* red) {
  int t = threadIdx.x;
  #pragma unroll
  for (int off = 32; off; off >>= 1) v += __shfl_down(v, off);
  if ((t & 63) == 0) red[t >> 6] = v;
  __syncthreads();
  if (t == 0) red[0] = red[0] + red[1] + red[2] + red[3];
  __syncthreads();
  return red[0];
}

__global__ __launch_bounds__(256) void mmore_attn_dp(
    const int* __restrict__ dxseqs, const float* __restrict__ base,
    const float* __restrict__ pe, const float* __restrict__ po,
    const float* __restrict__ combW, const float* __restrict__ combB,
    const float* __restrict__ ehr_table, const float* __restrict__ onto_all,
    const float* __restrict__ dpW, const float* __restrict__ dpB,
    float* __restrict__ out) {
  __shared__ float base_s[128];
  __shared__ int idx_s[kN];
  __shared__ float scp[kN][2];
  __shared__ float attn_s[64];
  __shared__ float tn_s[256];
  __shared__ __align__(16) float up[2][kDPL];
  __shared__ __align__(16) float e_s[kDPL];
  __shared__ float red[4];
  int bt = blockIdx.x, t = threadIdx.x;
  if (t < 128) base_s[t] = base[bt * 128 + t];
  if (t < kN) idx_s[t] = dxseqs[bt * kN + t];
  __syncthreads();
  int c = t & 127, half = t >> 7, wid = t >> 6, lane = t & 63;
  float cw = combW[c];
  for (int n2 = 0; n2 < kN / 2; ++n2) {
    int n = n2 * 2 + half;
    int id = idx_s[n];
    float x = base_s[c] + pe[(size_t)id * 128 + c] + po[(size_t)id * 128 + c];
    float val = tanhf(x) * cw;
    #pragma unroll
    for (int off = 32; off; off >>= 1) val += __shfl_down(val, off);
    if (lane == 0) scp[n][wid & 1] = val;
  }
  __syncthreads();
  if (t < 64) {
    float s = (t < kN) ? (scp[t][0] + scp[t][1] + combB[0]) : -1e30f;
    float mx = s;
    #pragma unroll
    for (int off = 32; off; off >>= 1) mx = fmaxf(mx, __shfl_xor(mx, off));
    float e = (t < kN) ? expf(s - mx) : 0.f;
    float sm = e;
    #pragma unroll
    for (int off = 32; off; off >>= 1) sm += __shfl_xor(sm, off);
    attn_s[t] = e / sm;
  }
  __syncthreads();
  float acc = 0.f;
  {
    const float* tab = (t < 128) ? ehr_table : onto_all;
    int j = t & 127;
    for (int n = 0; n < kN; ++n)
      acc += attn_s[n] * tab[(size_t)idx_s[n] * 128 + j];
  }
  float ss = mmore_block_sum(acc * acc, red);
  float inv = 1.f / fmaxf(sqrtf(ss), 1e-12f);
  tn_s[t] = tanhf(acc * inv);
  __syncthreads();
  if (t < 250) {
    int j4 = (t % 125) * 4, kh = t / 125;
    float ax = 0.f, ay = 0.f, az = 0.f, aw = 0.f;
    const float* wp = dpW + j4;
    for (int k = kh * 128; k < kh * 128 + 128; ++k) {
      float tv = tn_s[k];
      f4 w4 = *(const f4*)(wp + (size_t)k * kDPL);
      ax += tv * w4.x; ay += tv * w4.y; az += tv * w4.z; aw += tv * w4.w;
    }
    *(f4*)&up[kh][j4] = make_float4(ax, ay, az, aw);
  }
  __syncthreads();
  float psum = 0.f;
  if (t < 125) {
    int j4 = t * 4;
    float u0 = up[0][j4 + 0] + up[1][j4 + 0] + dpB[j4 + 0];
    float u1 = up[0][j4 + 1] + up[1][j4 + 1] + dpB[j4 + 1];
    float u2 = up[0][j4 + 2] + up[1][j4 + 2] + dpB[j4 + 2];
    float u3 = up[0][j4 + 3] + up[1][j4 + 3] + dpB[j4 + 3];
    float e0 = expf(u0), e1 = expf(u1), e2 = expf(u2), e3 = expf(u3);
    *(f4*)&e_s[j4] = make_float4(e0, e1, e2, e3);
    psum = e0 + e1 + e2 + e3;
  }
  float S = mmore_block_sum(psum, red);
  if (t < 125) {
    float invS = 1.f / S;
    f4 e = *(const f4*)&e_s[t * 4];
    *(f4*)(out + (size_t)bt * kDPL + t * 4) =
        make_float4(e.x * invS, e.y * invS, e.z * invS, e.w * invS);
  }
}

extern "C" void kernel_launch(void* const* d_in, const int* in_sizes, int n_in,
                              void* d_out, int out_size, void* d_ws, size_t ws_size,
                              hipStream_t stream) {
  const int*   dxseqs     = (const int*)d_in[0];
  const float* dx_onehot  = (const float*)d_in[1];
  const int*   leaves     = (const int*)d_in[2];
  const int*   ancestors  = (const int*)d_in[3];
  const float* onto_table = (const float*)d_in[4];
  const float* onto_Wa    = (const float*)d_in[5];
  const float* onto_ba    = (const float*)d_in[6];
  const float* onto_Wc    = (const float*)d_in[7];
  const float* onto_bc    = (const float*)d_in[8];
  const float* ehr_table  = (const float*)d_in[9];
  const float* attn_W     = (const float*)d_in[10];
  const float* attn_b     = (const float*)d_in[11];
  const float* comb_W     = (const float*)d_in[12];
  const float* comb_b     = (const float*)d_in[13];
  const float* co_W       = (const float*)d_in[14];
  const float* co_b       = (const float*)d_in[15];
  const float* dp_W       = (const float*)d_in[16];
  const float* dp_b       = (const float*)d_in[17];
  float* out = (float*)d_out;

  // workspace layout (floats) — ~25.1 MB total, same footprint as R1.
  // cpart (12*2048*128 = 3,145,728 fl) ALIASES pe..term (3,309,824 fl): it is
  // fully consumed by creduce before the pe/po/basep/epart region is written.
  float* ws = (float*)d_ws;
  float* onto_all = ws;  ws += (size_t)(kV + 1) * kO;   // 1280128
  float* s_sc = ws;      ws += (size_t)kV * kL;         // 60000
  float* ehrV = ws;      ws += (size_t)kBT * kE;        // 262144
  float* ontoV = ws;     ws += (size_t)kBT * kO;        // 262144
  float* pe = ws;        ws += (size_t)(kV + 1) * 128;  // 1280128
  float* po = ws;        ws += (size_t)(kV + 1) * 128;  // 1280128
  float* basep = ws;     ws += (size_t)kBT * 128;       // 262144
  float* epart = ws;     ws += (size_t)kVT * kBT * 3;   // 485376
  float* term = ws;      ws += kBT;                     // 2048
  float* cpart = pe;                                    // alias (see above)

  mmore_ehrv<<<kBT, 128, 0, stream>>>(dxseqs, ehr_table, ehrV);
  mmore_scores<<<(kV * kL) / 32, 256, 0, stream>>>(onto_table, leaves, ancestors,
                                                   onto_Wa, onto_ba, onto_Wc, onto_bc, s_sc);
  mmore_onto<<<kV + 1, 128, 0, stream>>>(onto_table, ancestors, s_sc, onto_all);
  mmore_ontov<<<64 * kC, 256, 0, stream>>>(dx_onehot, onto_all, cpart);
  mmore_creduce<<<(kBT * kO) / 256, 256, 0, stream>>>(cpart, ontoV);
  mmore_lossgemm<<<64 * kVT, 256, 0, stream>>>(ehrV, co_W, co_b, dx_onehot, epart);
  mmore_gemm128<<<313, 256, 0, stream>>>(ehr_table, attn_W + 256 * 128, nullptr, pe, kV + 1, 0);
  mmore_gemm128<<<313, 256, 0, stream>>>(onto_all, attn_W + 384 * 128, nullptr, po, kV + 1, 0);
  mmore_gemm128<<<64, 256, 0, stream>>>(ontoV, attn_W, nullptr, basep, kBT, 0);
  mmore_gemm128<<<64, 256, 0, stream>>>(ehrV, attn_W + 128 * 128, attn_b, basep, kBT, 1);
  mmore_ereduce<<<kBT / 256, 256, 0, stream>>>(epart, term);
  mmore_lossfin<<<1, 256, 0, stream>>>(term, out + (size_t)kBT * kDPL);
  mmore_attn_dp<<<kBT, 256, 0, stream>>>(dxseqs, basep, pe, po, comb_W, comb_b,
                                         ehr_table, onto_all, dp_W, dp_b, out);
}

// Round 3
// 291.707 us; speedup vs baseline: 1.7463x; 1.4307x over previous
//
#include <hip/hip_runtime.h>
#include <math.h>

typedef float4 f4;
typedef __bf16 bf16x8 __attribute__((ext_vector_type(8)));
typedef float f32x4 __attribute__((ext_vector_type(4)));

static constexpr int kV = 10000, kL = 6, kDPL = 500;
static constexpr int kB = 64, kT = 32, kN = 40, kBT = 2048;
static constexpr int kC = 8, kKPER = 1280;   // K-split for ontoV mfma
static constexpr int kVT = 79;               // ceil(10000/128) v-tiles
static constexpr int kOntoLd = 10240;        // ontoT row stride (k-pad)
static constexpr int kVpad = 10112;          // coWT rows (n-pad)

#define MFMA16 __builtin_amdgcn_mfma_f32_16x16x32_bf16

__device__ __forceinline__ bf16x8 cvt8(f4 a, f4 b) {
  bf16x8 r;
  r[0] = (__bf16)a.x; r[1] = (__bf16)a.y; r[2] = (__bf16)a.z; r[3] = (__bf16)a.w;
  r[4] = (__bf16)b.x; r[5] = (__bf16)b.y; r[6] = (__bf16)b.z; r[7] = (__bf16)b.w;
  return r;
}

// ---------------- fp32 -> bf16 elementwise ----------------
__global__ __launch_bounds__(256) void mmore_cvt_bf16(
    const float* __restrict__ in, __bf16* __restrict__ out, int n) {
  int i = (blockIdx.x * 256 + threadIdx.x) * 8;
  if (i < n) {
    f4 a = *(const f4*)(in + i), b = *(const f4*)(in + i + 4);
    *(bf16x8*)(out + i) = cvt8(a, b);
  }
}

// ---------------- transpose+cvt: out[n][k] (bf16, k-pad/n-pad zeros) = in[k][n]
// grid: (Kpad/128, Npad/16), block 256. in rows=K, cols=N.
__global__ __launch_bounds__(256) void mmore_trcvt(
    const float* __restrict__ in, __bf16* __restrict__ out,
    int K, int N, int Kpad) {
  int t = threadIdx.x;
  int n = blockIdx.y * 16 + (t & 15);
  int kb = (blockIdx.x * 16 + (t >> 4)) * 8;
  bf16x8 r;
  #pragma unroll
  for (int i = 0; i < 8; ++i) {
    int k = kb + i;
    float v = (k < K && n < N) ? in[(size_t)k * N + n] : 0.f;
    r[i] = (__bf16)v;
  }
  *(bf16x8*)(out + (size_t)n * Kpad + kb) = r;
}

// ---------------- ehrV = l2norm(sum_n ehr_table[dxseqs]) ----------------
__global__ __launch_bounds__(128) void mmore_ehrv(
    const int* __restrict__ dxseqs, const float* __restrict__ ehr_table,
    float* __restrict__ ehrV) {
  int bt = blockIdx.x, t = threadIdx.x;
  const int* row = dxseqs + bt * kN;
  float acc = 0.f;
  for (int n = 0; n < kN; ++n) acc += ehr_table[(size_t)row[n] * 128 + t];
  float v = acc * acc;
  #pragma unroll
  for (int off = 32; off; off >>= 1) v += __shfl_down(v, off);
  __shared__ float red[2];
  if ((t & 63) == 0) red[t >> 6] = v;
  __syncthreads();
  float ss = red[0] + red[1];
  float inv = 1.f / fmaxf(sqrtf(ss), 1e-12f);
  ehrV[bt * 128 + t] = acc * inv;
}

// ---------------- GRAM scores via MFMA: s = Wc . tanh([el,ea]@Wa + ba) + bc --
__global__ __launch_bounds__(256) void mmore_scores_mfma(
    const __bf16* __restrict__ otb, const int* __restrict__ leaves,
    const int* __restrict__ anc, const __bf16* __restrict__ WaT,
    const float* __restrict__ ba, const float* __restrict__ Wc,
    const float* __restrict__ bc, float* __restrict__ s_out) {
  int t = threadIdx.x, wave = t >> 6, lane = t & 63, lm = lane & 15, lg = lane >> 4;
  int r0 = blockIdx.x * 32;
  int rA0 = r0 + lm, rA1 = rA0 + 16;
  int v0 = rA0 / 6, l0 = rA0 - v0 * 6, v1 = rA1 / 6, l1 = rA1 - v1 * 6;
  const __bf16* pL0 = otb + (size_t)leaves[v0 * 6 + l0] * 128;
  const __bf16* pA0 = otb + (size_t)anc[v0 * 6 + l0] * 128;
  const __bf16* pL1 = otb + (size_t)leaves[v1 * 6 + l1] * 128;
  const __bf16* pA1 = otb + (size_t)anc[v1 * 6 + l1] * 128;
  const __bf16* bp = WaT + (size_t)(wave * 32 + lm) * 256 + lg * 8;
  f32x4 acc[2][2] = {};
  #pragma unroll
  for (int kb = 0; kb < 256; kb += 32) {
    int k = kb + lg * 8;
    const __bf16* s0 = (k < 128) ? (pL0 + k) : (pA0 + (k - 128));
    const __bf16* s1 = (k < 128) ? (pL1 + k) : (pA1 + (k - 128));
    bf16x8 a0 = *(const bf16x8*)s0;
    bf16x8 a1 = *(const bf16x8*)s1;
    bf16x8 b0 = *(const bf16x8*)(bp + kb);
    bf16x8 b1 = *(const bf16x8*)(bp + kb + 16 * 256);
    acc[0][0] = MFMA16(a0, b0, acc[0][0], 0, 0, 0);
    acc[0][1] = MFMA16(a0, b1, acc[0][1], 0, 0, 0);
    acc[1][0] = MFMA16(a1, b0, acc[1][0], 0, 0, 0);
    acc[1][1] = MFMA16(a1, b1, acc[1][1], 0, 0, 0);
  }
  __shared__ float red[4][32];
  float bcv = bc[0];
  #pragma unroll
  for (int mf = 0; mf < 2; ++mf) {
    #pragma unroll
    for (int j = 0; j < 4; ++j) {
      float p = 0.f;
      #pragma unroll
      for (int nf = 0; nf < 2; ++nf) {
        int c = wave * 32 + nf * 16 + lm;
        p += tanhf(acc[mf][nf][j] + ba[c]) * Wc[c];
      }
      #pragma unroll
      for (int off = 8; off; off >>= 1) p += __shfl_xor(p, off);
      if (lm == 0) red[wave][mf * 16 + lg * 4 + j] = p;
    }
  }
  __syncthreads();
  if (t < 32) s_out[r0 + t] = red[0][t] + red[1][t] + red[2][t] + red[3][t] + bcv;
}

// ---------------- onto_all[v] = softmax_l(s) . ea ; row V = 0 ----------------
__global__ __launch_bounds__(128) void mmore_onto(
    const float* __restrict__ ot, const int* __restrict__ anc,
    const float* __restrict__ s_in, float* __restrict__ onto_all) {
  int v = blockIdx.x, t = threadIdx.x;
  if (v == kV) { onto_all[(size_t)v * 128 + t] = 0.f; return; }
  __shared__ float sv[kL];
  __shared__ int aidx[kL];
  if (t < kL) { sv[t] = s_in[v * kL + t]; aidx[t] = anc[v * kL + t]; }
  __syncthreads();
  float mx = sv[0];
  #pragma unroll
  for (int l = 1; l < kL; ++l) mx = fmaxf(mx, sv[l]);
  float e[kL], sum = 0.f;
  #pragma unroll
  for (int l = 0; l < kL; ++l) { e[l] = expf(sv[l] - mx); sum += e[l]; }
  float acc = 0.f;
  #pragma unroll
  for (int l = 0; l < kL; ++l)
    acc += (e[l] / sum) * ot[(size_t)aidx[l] * 128 + t];
  onto_all[(size_t)v * 128 + t] = acc;
}

// ---------------- ontoV partials via MFMA: X(bt,v) @ onto_all, 8-way K-split --
__global__ __launch_bounds__(256) void mmore_ontov_mfma(
    const float* __restrict__ X, const __bf16* __restrict__ BT,
    float* __restrict__ part) {
  int t = threadIdx.x, wave = t >> 6, lane = t & 63, lm = lane & 15, lg = lane >> 4;
  int btile = blockIdx.x & 63, chunk = blockIdx.x >> 6;
  int r0 = btile * 32, vbase = chunk * kKPER;
  int Klim = kV - vbase; if (Klim > kKPER) Klim = kKPER;
  int bt0 = r0 + lm, bt1 = bt0 + 16;
  const float* a0 = X + ((size_t)(bt0 & 31) * kB + (bt0 >> 5)) * kV + vbase + lg * 8;
  const float* a1 = X + ((size_t)(bt1 & 31) * kB + (bt1 >> 5)) * kV + vbase + lg * 8;
  const __bf16* bp = BT + (size_t)(wave * 32 + lm) * kOntoLd + vbase + lg * 8;
  f32x4 acc[2][2] = {};
  for (int kb = 0; kb < Klim; kb += 32) {
    bool ka = (vbase + kb + lg * 8) < kV;   // 8-aligned, kV%8==0
    f4 x0 = make_float4(0, 0, 0, 0), x1 = x0, y0 = x0, y1 = x0;
    if (ka) {
      x0 = *(const f4*)(a0 + kb); x1 = *(const f4*)(a0 + kb + 4);
      y0 = *(const f4*)(a1 + kb); y1 = *(const f4*)(a1 + kb + 4);
    }
    bf16x8 af0 = cvt8(x0, x1), af1 = cvt8(y0, y1);
    bf16x8 b0 = *(const bf16x8*)(bp + kb);
    bf16x8 b1 = *(const bf16x8*)(bp + kb + 16 * kOntoLd);
    acc[0][0] = MFMA16(af0, b0, acc[0][0], 0, 0, 0);
    acc[0][1] = MFMA16(af0, b1, acc[0][1], 0, 0, 0);
    acc[1][0] = MFMA16(af1, b0, acc[1][0], 0, 0, 0);
    acc[1][1] = MFMA16(af1, b1, acc[1][1], 0, 0, 0);
  }
  #pragma unroll
  for (int mf = 0; mf < 2; ++mf)
    #pragma unroll
    for (int nf = 0; nf < 2; ++nf) {
      int col = wave * 32 + nf * 16 + lm;
      #pragma unroll
      for (int j = 0; j < 4; ++j) {
        int row = r0 + mf * 16 + lg * 4 + j;
        part[((size_t)chunk * kBT + row) * 128 + col] = acc[mf][nf][j];
      }
    }
}

__global__ __launch_bounds__(256) void mmore_creduce(
    const float* __restrict__ part, float* __restrict__ out) {
  int i = blockIdx.x * 256 + threadIdx.x;
  const int S = kBT * 128;
  float a = 0.f;
  #pragma unroll
  for (int c = 0; c < kC; ++c) a += part[(size_t)c * S + i];
  out[i] = a;
}

// ---------------- loss via MFMA: z = ehrV@coW + cob; partials {Σe^z, Σp·z, Σp}
__global__ __launch_bounds__(256) void mmore_loss_mfma(
    const float* __restrict__ ehrV, const __bf16* __restrict__ coWT,
    const float* __restrict__ cob, const float* __restrict__ X,
    float* __restrict__ epart) {
  int t = threadIdx.x, wave = t >> 6, lane = t & 63, lm = lane & 15, lg = lane >> 4;
  int vtile = blockIdx.x, btile = blockIdx.y;
  int r0 = btile * 32, vb = vtile * 128;
  const float* a0 = ehrV + (size_t)(r0 + lm) * 128 + lg * 8;
  const float* a1 = a0 + 16 * 128;
  const __bf16* bp = coWT + (size_t)(vb + wave * 32 + lm) * 128 + lg * 8;
  f32x4 acc[2][2] = {};
  #pragma unroll
  for (int kb = 0; kb < 128; kb += 32) {
    f4 x0 = *(const f4*)(a0 + kb), x1 = *(const f4*)(a0 + kb + 4);
    f4 y0 = *(const f4*)(a1 + kb), y1 = *(const f4*)(a1 + kb + 4);
    bf16x8 af0 = cvt8(x0, x1), af1 = cvt8(y0, y1);
    bf16x8 b0 = *(const bf16x8*)(bp + kb);
    bf16x8 b1 = *(const bf16x8*)(bp + kb + 16 * 128);
    acc[0][0] = MFMA16(af0, b0, acc[0][0], 0, 0, 0);
    acc[0][1] = MFMA16(af0, b1, acc[0][1], 0, 0, 0);
    acc[1][0] = MFMA16(af1, b0, acc[1][0], 0, 0, 0);
    acc[1][1] = MFMA16(af1, b1, acc[1][1], 0, 0, 0);
  }
  float se[2][4] = {}, spz[2][4] = {}, sp[2][4] = {};
  #pragma unroll
  for (int nf = 0; nf < 2; ++nf) {
    int c = vb + wave * 32 + nf * 16 + lm;
    if (c < kV) {
      float cb = cob[c];
      #pragma unroll
      for (int mf = 0; mf < 2; ++mf) {
        #pragma unroll
        for (int j = 0; j < 4; ++j) {
          int row = r0 + mf * 16 + lg * 4 + j;
          float z = acc[mf][nf][j] + cb;
          float p = X[((size_t)(row & 31) * kB + (row >> 5)) * kV + c];
          se[mf][j] += __expf(z);
          spz[mf][j] += p * z;
          sp[mf][j] += p;
        }
      }
    }
  }
  __shared__ float red[4][32][3];
  #pragma unroll
  for (int mf = 0; mf < 2; ++mf)
    #pragma unroll
    for (int j = 0; j < 4; ++j) {
      float a = se[mf][j], b = spz[mf][j], d = sp[mf][j];
      #pragma unroll
      for (int off = 8; off; off >>= 1) {
        a += __shfl_xor(a, off); b += __shfl_xor(b, off); d += __shfl_xor(d, off);
      }
      if (lm == 0) {
        int r = mf * 16 + lg * 4 + j;
        red[wave][r][0] = a; red[wave][r][1] = b; red[wave][r][2] = d;
      }
    }
  __syncthreads();
  if (t < 96) {
    int r = t / 3, q = t - (t / 3) * 3;
    float s = red[0][r][q] + red[1][r][q] + red[2][r][q] + red[3][r][q];
    epart[((size_t)vtile * kBT + r0 + r) * 3 + q] = s;
  }
}

__global__ __launch_bounds__(256) void mmore_ereduce(
    const float* __restrict__ epart, float* __restrict__ term) {
  int bt = blockIdx.x * 256 + threadIdx.x;
  float S = 0.f, PZ = 0.f, PS = 0.f;
  for (int c = 0; c < kVT; ++c) {
    size_t o = ((size_t)c * kBT + bt) * 3;
    S += epart[o]; PZ += epart[o + 1]; PS += epart[o + 2];
  }
  term[bt] = PZ - PS * logf(S);
}

__global__ __launch_bounds__(256) void mmore_lossfin(
    const float* __restrict__ term, float* __restrict__ out) {
  int t = threadIdx.x;
  float a = 0.f;
  for (int i = t; i < kBT; i += 256) a += term[i];
  #pragma unroll
  for (int off = 32; off; off >>= 1) a += __shfl_down(a, off);
  __shared__ float red[4];
  if ((t & 63) == 0) red[t >> 6] = a;
  __syncthreads();
  if (t == 0) out[0] = -(10.f / 64.f) * (red[0] + red[1] + red[2] + red[3]);
}

// ---------------- generic MFMA: C[M][128] (+=) A[M][128] @ WT[n][ldWT]+koff --
__global__ __launch_bounds__(256) void mmore_gemm_mfma(
    const float* __restrict__ A, const __bf16* __restrict__ WT,
    int ldWT, int koff, const float* __restrict__ bias,
    float* __restrict__ C, int M, int accumulate) {
  int t = threadIdx.x, wave = t >> 6, lane = t & 63, lm = lane & 15, lg = lane >> 4;
  int r0 = blockIdx.x * 32;
  int row0 = r0 + lm, row1 = row0 + 16;
  bool ok0 = row0 < M, ok1 = row1 < M;
  const float* a0 = A + (size_t)row0 * 128 + lg * 8;
  const float* a1 = A + (size_t)row1 * 128 + lg * 8;
  const __bf16* bp = WT + (size_t)(wave * 32 + lm) * ldWT + koff + lg * 8;
  int ld16 = 16 * ldWT;
  f32x4 acc[2][2] = {};
  #pragma unroll
  for (int kb = 0; kb < 128; kb += 32) {
    f4 x0 = make_float4(0, 0, 0, 0), x1 = x0, y0 = x0, y1 = x0;
    if (ok0) { x0 = *(const f4*)(a0 + kb); x1 = *(const f4*)(a0 + kb + 4); }
    if (ok1) { y0 = *(const f4*)(a1 + kb); y1 = *(const f4*)(a1 + kb + 4); }
    bf16x8 af0 = cvt8(x0, x1), af1 = cvt8(y0, y1);
    bf16x8 b0 = *(const bf16x8*)(bp + kb);
    bf16x8 b1 = *(const bf16x8*)(bp + kb + ld16);
    acc[0][0] = MFMA16(af0, b0, acc[0][0], 0, 0, 0);
    acc[0][1] = MFMA16(af0, b1, acc[0][1], 0, 0, 0);
    acc[1][0] = MFMA16(af1, b0, acc[1][0], 0, 0, 0);
    acc[1][1] = MFMA16(af1, b1, acc[1][1], 0, 0, 0);
  }
  #pragma unroll
  for (int mf = 0; mf < 2; ++mf)
    #pragma unroll
    for (int nf = 0; nf < 2; ++nf) {
      int col = wave * 32 + nf * 16 + lm;
      #pragma unroll
      for (int j = 0; j < 4; ++j) {
        int row = r0 + mf * 16 + lg * 4 + j;
        if (row < M) {
          float v = acc[mf][nf][j];
          if (bias) v += bias[col];
          if (accumulate) v += C[(size_t)row * 128 + col];
          C[(size_t)row * 128 + col] = v;
        }
      }
    }
}

// ---------------- per-(b,t): Bahdanau attention -> tn = tanh(l2norm(vs2)) ----
__device__ __forceinline__ float mmore_block_sum(float v, float* red) {
  int t = threadIdx.x;
  #pragma unroll
  for (int off = 32; off; off >>= 1) v += __shfl_down(v, off);
  if ((t & 63) == 0) red[t >> 6] = v;
  __syncthreads();
  if (t == 0) red[0] = red[0] + red[1] + red[2] + red[3];
  __syncthreads();
  return red[0];
}

__global__ __launch_bounds__(256) void mmore_attn(
    const int* __restrict__ dxseqs, const float* __restrict__ base,
    const float* __restrict__ pe, const float* __restrict__ po,
    const float* __restrict__ combW, const float* __restrict__ combB,
    const float* __restrict__ ehr_table, const float* __restrict__ onto_all,
    float* __restrict__ tn) {
  __shared__ float base_s[128];
  __shared__ int idx_s[kN];
  __shared__ float scp[kN][2];
  __shared__ float attn_s[64];
  __shared__ float red[4];
  int bt = blockIdx.x, t = threadIdx.x;
  if (t < 128) base_s[t] = base[bt * 128 + t];
  if (t < kN) idx_s[t] = dxseqs[bt * kN + t];
  __syncthreads();
  int c = t & 127, half = t >> 7, wid = t >> 6, lane = t & 63;
  float cw = combW[c];
  for (int n2 = 0; n2 < kN / 2; ++n2) {
    int n = n2 * 2 + half;
    int id = idx_s[n];
    float x = base_s[c] + pe[(size_t)id * 128 + c] + po[(size_t)id * 128 + c];
    float val = tanhf(x) * cw;
    #pragma unroll
    for (int off = 32; off; off >>= 1) val += __shfl_down(val, off);
    if (lane == 0) scp[n][wid & 1] = val;
  }
  __syncthreads();
  if (t < 64) {
    float s = (t < kN) ? (scp[t][0] + scp[t][1] + combB[0]) : -1e30f;
    float mx = s;
    #pragma unroll
    for (int off = 32; off; off >>= 1) mx = fmaxf(mx, __shfl_xor(mx, off));
    float e = (t < kN) ? __expf(s - mx) : 0.f;
    float sm = e;
    #pragma unroll
    for (int off = 32; off; off >>= 1) sm += __shfl_xor(sm, off);
    attn_s[t] = e / sm;
  }
  __syncthreads();
  float acc = 0.f;
  {
    const float* tab = (t < 128) ? ehr_table : onto_all;
    int j = t & 127;
    for (int n = 0; n < kN; ++n)
      acc += attn_s[n] * tab[(size_t)idx_s[n] * 128 + j];
  }
  float ss = mmore_block_sum(acc * acc, red);
  float inv = 1.f / fmaxf(sqrtf(ss), 1e-12f);
  tn[(size_t)bt * 256 + t] = tanhf(acc * inv);
}

// ---------------- dp head GEMM: u[2048][512] = tn@dpWT + dpB ----------------
__global__ __launch_bounds__(256) void mmore_dpgemm(
    const float* __restrict__ tn, const __bf16* __restrict__ dpWT,
    const float* __restrict__ dpB, float* __restrict__ u) {
  int t = threadIdx.x, wave = t >> 6, lane = t & 63, lm = lane & 15, lg = lane >> 4;
  int c0 = blockIdx.x * 128, r0 = blockIdx.y * 32;
  const float* a0 = tn + (size_t)(r0 + lm) * 256 + lg * 8;
  const float* a1 = a0 + 16 * 256;
  const __bf16* bp = dpWT + (size_t)(c0 + wave * 32 + lm) * 256 + lg * 8;
  f32x4 acc[2][2] = {};
  #pragma unroll
  for (int kb = 0; kb < 256; kb += 32) {
    f4 x0 = *(const f4*)(a0 + kb), x1 = *(const f4*)(a0 + kb + 4);
    f4 y0 = *(const f4*)(a1 + kb), y1 = *(const f4*)(a1 + kb + 4);
    bf16x8 af0 = cvt8(x0, x1), af1 = cvt8(y0, y1);
    bf16x8 b0 = *(const bf16x8*)(bp + kb);
    bf16x8 b1 = *(const bf16x8*)(bp + kb + 16 * 256);
    acc[0][0] = MFMA16(af0, b0, acc[0][0], 0, 0, 0);
    acc[0][1] = MFMA16(af0, b1, acc[0][1], 0, 0, 0);
    acc[1][0] = MFMA16(af1, b0, acc[1][0], 0, 0, 0);
    acc[1][1] = MFMA16(af1, b1, acc[1][1], 0, 0, 0);
  }
  #pragma unroll
  for (int mf = 0; mf < 2; ++mf)
    #pragma unroll
    for (int nf = 0; nf < 2; ++nf) {
      int col = c0 + wave * 32 + nf * 16 + lm;
      float bias = (col < kDPL) ? dpB[col] : 0.f;
      #pragma unroll
      for (int j = 0; j < 4; ++j) {
        int row = r0 + mf * 16 + lg * 4 + j;
        u[(size_t)row * 512 + col] = acc[mf][nf][j] + bias;
      }
    }
}

// ---------------- dp softmax over 500 cols ----------------
__global__ __launch_bounds__(128) void mmore_dpsoft(
    const float* __restrict__ u, float* __restrict__ out) {
  int bt = blockIdx.x, t = threadIdx.x;
  __shared__ float red[2];
  float v[4]; float mx = -1e30f;
  #pragma unroll
  for (int i = 0; i < 4; ++i) {
    int c = t + i * 128;
    v[i] = (c < kDPL) ? u[(size_t)bt * 512 + c] : -1e30f;
    mx = fmaxf(mx, v[i]);
  }
  #pragma unroll
  for (int off = 32; off; off >>= 1) mx = fmaxf(mx, __shfl_xor(mx, off));
  if ((t & 63) == 0) red[t >> 6] = mx;
  __syncthreads();
  mx = fmaxf(red[0], red[1]);
  __syncthreads();
  float e[4], s = 0.f;
  #pragma unroll
  for (int i = 0; i < 4; ++i) {
    int c = t + i * 128;
    e[i] = (c < kDPL) ? __expf(v[i] - mx) : 0.f;
    s += e[i];
  }
  #pragma unroll
  for (int off = 32; off; off >>= 1) s += __shfl_xor(s, off);
  if ((t & 63) == 0) red[t >> 6] = s;
  __syncthreads();
  float invS = 1.f / (red[0] + red[1]);
  #pragma unroll
  for (int i = 0; i < 4; ++i) {
    int c = t + i * 128;
    if (c < kDPL) out[(size_t)bt * kDPL + c] = e[i] * invS;
  }
}

extern "C" void kernel_launch(void* const* d_in, const int* in_sizes, int n_in,
                              void* d_out, int out_size, void* d_ws, size_t ws_size,
                              hipStream_t stream) {
  const int*   dxseqs     = (const int*)d_in[0];
  const float* dx_onehot  = (const float*)d_in[1];
  const int*   leaves     = (const int*)d_in[2];
  const int*   ancestors  = (const int*)d_in[3];
  const float* onto_table = (const float*)d_in[4];
  const float* onto_Wa    = (const float*)d_in[5];
  const float* onto_ba    = (const float*)d_in[6];
  const float* onto_Wc    = (const float*)d_in[7];
  const float* onto_bc    = (const float*)d_in[8];
  const float* ehr_table  = (const float*)d_in[9];
  const float* attn_W     = (const float*)d_in[10];
  const float* attn_b     = (const float*)d_in[11];
  const float* comb_W     = (const float*)d_in[12];
  const float* comb_b     = (const float*)d_in[13];
  const float* co_W       = (const float*)d_in[14];
  const float* co_b       = (const float*)d_in[15];
  const float* dp_W       = (const float*)d_in[16];
  const float* dp_b       = (const float*)d_in[17];
  float* out = (float*)d_out;

  // ---- workspace (float slots), ~26.4 MB total ----
  float* ws = (float*)d_ws;
  size_t off = 0;
  auto alloc = [&](size_t n) { float* p = ws + off; off += n; return p; };
  float* onto_all = alloc((size_t)(kV + 1) * 128);  // 1,280,128
  float* s_sc     = alloc((size_t)kV * kL);          //    60,000
  float* ehrV     = alloc((size_t)kBT * 128);        //   262,144  (tn aliases ehrV+ontoV)
  float* ontoV    = alloc((size_t)kBT * 128);        //   262,144
  float* peR      = alloc((size_t)(kV + 1) * 128);   // 1,280,128  (ot_bf/cpart/u alias here)
  float* poR      = alloc((size_t)(kV + 1) * 128);   // 1,280,128  (cpart tail spills here)
  float* basep    = alloc((size_t)kBT * 128);        //   262,144
  float* epart    = alloc((size_t)kVT * kBT * 3);    //   485,376
  float* term     = alloc(kBT);                      //     2,048
  __bf16* ontoT   = (__bf16*)alloc((size_t)128 * kOntoLd / 2);  // 655,360 fl
  __bf16* coWT    = (__bf16*)alloc((size_t)kVpad * 128 / 2);    // 647,168 fl
  __bf16* attn_WT = (__bf16*)alloc((size_t)128 * 512 / 2);      //  32,768 fl
  __bf16* dpWT    = (__bf16*)alloc((size_t)512 * 256 / 2);      //  65,536 fl
  __bf16* WaT     = (__bf16*)alloc((size_t)128 * 256 / 2);      //  16,384 fl
  // time-disjoint aliases:
  __bf16* ot_bf = (__bf16*)peR;   // dead after scores; before cpart
  float*  cpart = peR;            // dead after creduce; before pe/po written
  float*  u     = peR;            // written after pe last read (attn)
  float*  tn    = ehrV;           // written after ehrV/ontoV last reads

  // ---- prep: bf16 conversions / transposes ----
  mmore_cvt_bf16<<<663, 256, 0, stream>>>(onto_table, ot_bf, 10600 * 128);
  mmore_trcvt<<<dim3(2, 8), 256, 0, stream>>>(onto_Wa, WaT, 256, 128, 256);
  mmore_trcvt<<<dim3(1, 632), 256, 0, stream>>>(co_W, coWT, 128, kV, 128);
  mmore_trcvt<<<dim3(4, 8), 256, 0, stream>>>(attn_W, attn_WT, 512, 128, 512);
  mmore_trcvt<<<dim3(2, 32), 256, 0, stream>>>(dp_W, dpWT, 256, kDPL, 256);

  mmore_ehrv<<<kBT, 128, 0, stream>>>(dxseqs, ehr_table, ehrV);
  mmore_scores_mfma<<<(kV * kL) / 32, 256, 0, stream>>>(
      ot_bf, leaves, ancestors, WaT, onto_ba, onto_Wc, onto_bc, s_sc);
  mmore_onto<<<kV + 1, 128, 0, stream>>>(onto_table, ancestors, s_sc, onto_all);
  mmore_trcvt<<<dim3(80, 8), 256, 0, stream>>>(onto_all, ontoT, kV, 128, kOntoLd);
  mmore_ontov_mfma<<<64 * kC, 256, 0, stream>>>(dx_onehot, ontoT, cpart);
  mmore_creduce<<<(kBT * 128) / 256, 256, 0, stream>>>(cpart, ontoV);
  mmore_loss_mfma<<<dim3(kVT, 64), 256, 0, stream>>>(ehrV, coWT, co_b, dx_onehot, epart);
  mmore_ereduce<<<kBT / 256, 256, 0, stream>>>(epart, term);
  mmore_lossfin<<<1, 256, 0, stream>>>(term, out + (size_t)kBT * kDPL);
  mmore_gemm_mfma<<<313, 256, 0, stream>>>(ehr_table, attn_WT, 512, 256, nullptr, peR, kV + 1, 0);
  mmore_gemm_mfma<<<313, 256, 0, stream>>>(onto_all, attn_WT, 512, 384, nullptr, poR, kV + 1, 0);
  mmore_gemm_mfma<<<64, 256, 0, stream>>>(ontoV, attn_WT, 512, 0, nullptr, basep, kBT, 0);
  mmore_gemm_mfma<<<64, 256, 0, stream>>>(ehrV, attn_WT, 512, 128, attn_b, basep, kBT, 1);
  mmore_attn<<<kBT, 256, 0, stream>>>(dxseqs, basep, peR, poR, comb_W, comb_b,
                                      ehr_table, onto_all, tn);
  mmore_dpgemm<<<dim3(4, 64), 256, 0, stream>>>(tn, dpWT, dp_b, u);
  mmore_dpsoft<<<kBT, 128, 0, stream>>>(u, out);
}